// Round 2
// baseline (46960.428 us; speedup 1.0000x reference)
//
#include <hip/hip_runtime.h>

typedef _Float16 half2_t __attribute__((ext_vector_type(2)));

#define NB 64
#define NT 2048
#define ND 256
#define NH 256
#define NTHR 512

__device__ __forceinline__ float sigmoid_f(float x) {
    return 1.0f / (1.0f + __expf(-x));
}
__device__ __forceinline__ float tanh_f(float x) {
    return 1.0f - 2.0f / (1.0f + __expf(2.0f * x));
}
__device__ __forceinline__ half2_t mkh2(float a, float b) {
    half2_t r; r.x = (_Float16)a; r.y = (_Float16)b; return r;
}

// Grid: 256 WGs x 512 threads, persistent, 1 WG/CU. WG -> (batch, 64-col slice).
// Weights live in VGPRs as fp16 pairs (96 regs), dots via v_dot2_f32_f16.
// The 4 WGs of a batch are co-located per-XCD (bid&7) and exchange
// v = r*h_prev and h_new each step via agent-scope atomics + monotone flags.
extern "C" __global__ void __launch_bounds__(NTHR, 1)
gru_persistent(const float* __restrict__ x,
               const float* __restrict__ Wz, const float* __restrict__ bz,
               const float* __restrict__ Wr, const float* __restrict__ br,
               const float* __restrict__ Wh, const float* __restrict__ bh,
               float* __restrict__ out,
               float* hglob, float* vglob,
               unsigned* flagv, unsigned* flagh)
{
    __shared__ __align__(16) half2_t xbuf2[ND / 2];
    __shared__ __align__(16) half2_t hbuf2[NH / 2];
    __shared__ __align__(16) half2_t vbuf2[NH / 2];
    __shared__ __align__(16) float   hbuff[NH];     // fp32 h_prev (own slice used)
    __shared__ __align__(16) float   pz[8][64];
    __shared__ __align__(16) float   pr[8][64];
    __shared__ __align__(16) float   ph[8][64];

    const int tid = threadIdx.x;
    const int j   = tid & 63;      // lane
    const int p   = tid >> 6;      // wave id == k-chunk of 64
    const int bid = blockIdx.x;
    const int xcd   = bid & 7;
    const int slot  = bid >> 3;
    const int batch = xcd * 8 + (slot >> 2);
    const int slice = slot & 3;
    const int j0    = slice * 64;
    const int c     = j0 + j;      // output column this thread owns

    // ---- fp16-packed register weights: rows p*64..p*64+63, column c ----
    half2_t wz2[32], wr2[32], wh2[32];
    {
        const int rb = p * 64;
        #pragma unroll
        for (int i = 0; i < 32; ++i) {
            wz2[i] = mkh2(Wz[(rb + 2*i) * NH + c], Wz[(rb + 2*i + 1) * NH + c]);
            wr2[i] = mkh2(Wr[(rb + 2*i) * NH + c], Wr[(rb + 2*i + 1) * NH + c]);
            wh2[i] = mkh2(Wh[(rb + 2*i) * NH + c], Wh[(rb + 2*i + 1) * NH + c]);
        }
    }
    float bzv = 0.f, brv = 0.f, bhv = 0.f;
    if (p == 0) { bzv = bz[c]; bhv = bh[c]; }
    if (p == 1) { brv = br[c]; }

    // ---- init LDS state ----
    if (tid < NH / 2) { hbuf2[tid] = mkh2(0.f, 0.f); vbuf2[tid] = mkh2(0.f, 0.f); }
    if (tid < NH) hbuff[tid] = 0.f;
    if (p == 6) {  // x[batch][0][:]
        const float4 xv = *reinterpret_cast<const float4*>(
            &x[(size_t)batch * NT * ND + (size_t)j * 4]);
        xbuf2[2*j]     = mkh2(xv.x, xv.y);
        xbuf2[2*j + 1] = mkh2(xv.z, xv.w);
    }
    __syncthreads();

    const half2_t* inA2 = (p < 4) ? &xbuf2[p * 32] : &hbuf2[(p - 4) * 32];
    const half2_t* inB2 = (p < 4) ? &xbuf2[p * 32] : &vbuf2[(p - 4) * 32];

    float zreg = 0.f;   // p==0: z gate for own output
    float hreg = 0.f;   // p==0: own h_prev (fp32 recurrence)
    const size_t outbase = (size_t)batch * NT * NH + (size_t)c;

    for (int t = 0; t < NT; ++t) {
        // ---------- stage A: z,r partial dots over this wave's 64 k-values ----
        float az = 0.f, ar = 0.f;
        #pragma unroll
        for (int i = 0; i < 32; ++i) {
            const half2_t iv = inA2[i];
            az = __builtin_amdgcn_fdot2(iv, wz2[i], az, false);
            ar = __builtin_amdgcn_fdot2(iv, wr2[i], ar, false);
        }
        pz[p][j] = az;
        pr[p][j] = ar;
        __syncthreads();  // bar1

        if (p == 0) {
            float s = bzv;
            #pragma unroll
            for (int q = 0; q < 8; ++q) s += pz[q][j];
            zreg = sigmoid_f(s);
        } else if (p == 1) {
            float s = brv;
            #pragma unroll
            for (int q = 0; q < 8; ++q) s += pr[q][j];
            const float r = sigmoid_f(s);
            const float v = r * hbuff[c];
            const float vo = __shfl_xor(v, 1, 64);
            if (!(j & 1)) vbuf2[c >> 1] = mkh2(v, vo);
            __hip_atomic_store(&vglob[batch * NH + c], v,
                               __ATOMIC_RELAXED, __HIP_MEMORY_SCOPE_AGENT);
            asm volatile("s_waitcnt vmcnt(0)" ::: "memory");
            if (j == 0)
                __hip_atomic_store(&flagv[batch * 4 + slice], (unsigned)(t + 1),
                                   __ATOMIC_RELEASE, __HIP_MEMORY_SCOPE_AGENT);
        } else if (p == 7) {
            if (j < 3) {
                const int ps = (slice + 1 + j) & 3;
                unsigned iters = 0;
                while (__hip_atomic_load(&flagv[batch * 4 + ps],
                                         __ATOMIC_ACQUIRE, __HIP_MEMORY_SCOPE_AGENT)
                       < (unsigned)(t + 1)) {
                    __builtin_amdgcn_s_sleep(1);
                    if (++iters > (1u << 20)) break;
                }
            }
            #pragma unroll
            for (int q = 1; q <= 3; ++q) {
                const int ps = (slice + q) & 3;
                const float v = __hip_atomic_load(
                    &vglob[batch * NH + ps * 64 + j],
                    __ATOMIC_RELAXED, __HIP_MEMORY_SCOPE_AGENT);
                const float vo = __shfl_xor(v, 1, 64);
                if (!(j & 1)) vbuf2[(ps * 64 + j) >> 1] = mkh2(v, vo);
            }
        }
        __syncthreads();  // bar2: full v vector in vbuf2

        // ---------- stage B: h_hat partial dots over [x | v] ----------------
        float ah = 0.f;
        #pragma unroll
        for (int i = 0; i < 32; ++i) {
            ah = __builtin_amdgcn_fdot2(inB2[i], wh2[i], ah, false);
        }
        ph[p][j] = ah;
        __syncthreads();  // bar3

        if (p == 0) {
            float s = bhv;
            #pragma unroll
            for (int q = 0; q < 8; ++q) s += ph[q][j];
            const float hh = tanh_f(s);
            const float hn = (1.0f - zreg) * hreg + zreg * hh;
            hreg = hn;
            out[outbase + (size_t)t * NH] = hn;
            hbuff[c] = hn;
            const float ho = __shfl_xor(hn, 1, 64);
            if (!(j & 1)) hbuf2[c >> 1] = mkh2(hn, ho);
            __hip_atomic_store(&hglob[batch * NH + c], hn,
                               __ATOMIC_RELAXED, __HIP_MEMORY_SCOPE_AGENT);
            asm volatile("s_waitcnt vmcnt(0)" ::: "memory");
            if (j == 0)
                __hip_atomic_store(&flagh[batch * 4 + slice], (unsigned)(t + 1),
                                   __ATOMIC_RELEASE, __HIP_MEMORY_SCOPE_AGENT);
        } else if (p == 7) {
            if (j < 3) {
                const int ps = (slice + 1 + j) & 3;
                unsigned iters = 0;
                while (__hip_atomic_load(&flagh[batch * 4 + ps],
                                         __ATOMIC_ACQUIRE, __HIP_MEMORY_SCOPE_AGENT)
                       < (unsigned)(t + 1)) {
                    __builtin_amdgcn_s_sleep(1);
                    if (++iters > (1u << 20)) break;
                }
            }
            #pragma unroll
            for (int q = 1; q <= 3; ++q) {
                const int ps = (slice + q) & 3;
                const float hv = __hip_atomic_load(
                    &hglob[batch * NH + ps * 64 + j],
                    __ATOMIC_RELAXED, __HIP_MEMORY_SCOPE_AGENT);
                const float ho = __shfl_xor(hv, 1, 64);
                if (!(j & 1)) hbuf2[(ps * 64 + j) >> 1] = mkh2(hv, ho);
            }
        } else if (p == 6) {
            if (t + 1 < NT) {  // prefetch x[batch][t+1][:] into xbuf2
                const float4 xv = *reinterpret_cast<const float4*>(
                    &x[(size_t)batch * NT * ND + (size_t)(t + 1) * ND + (size_t)j * 4]);
                xbuf2[2*j]     = mkh2(xv.x, xv.y);
                xbuf2[2*j + 1] = mkh2(xv.z, xv.w);
            }
        }
        __syncthreads();  // bar4: hbuf2/hbuff = h_t, xbuf2 = x_{t+1}
    }
}

extern "C" void kernel_launch(void* const* d_in, const int* in_sizes, int n_in,
                              void* d_out, int out_size, void* d_ws, size_t ws_size,
                              hipStream_t stream) {
    const float* x  = (const float*)d_in[0];
    const float* Wz = (const float*)d_in[1];
    const float* bz = (const float*)d_in[2];
    const float* Wr = (const float*)d_in[3];
    const float* br = (const float*)d_in[4];
    const float* Wh = (const float*)d_in[5];
    const float* bh = (const float*)d_in[6];
    float* outp = (float*)d_out;

    float* hglob = (float*)d_ws;                     // [NB][NH]
    float* vglob = hglob + NB * NH;                  // [NB][NH]
    unsigned* flagv = (unsigned*)(vglob + NB * NH);  // [NB][4]
    unsigned* flagh = flagv + NB * 4;                // [NB][4]

    // flags must start at 0 every launch (monotone t+1 counters)
    hipMemsetAsync(flagv, 0, 2 * NB * 4 * sizeof(unsigned), stream);

    gru_persistent<<<256, NTHR, 0, stream>>>(x, Wz, bz, Wr, br, Wh, bh,
                                             outp, hglob, vglob, flagv, flagh);
}

// Round 3
// 3174.388 us; speedup vs baseline: 14.7935x; 14.7935x over previous
//
#include <hip/hip_runtime.h>

typedef _Float16 half2_t __attribute__((ext_vector_type(2)));

#define NB 64
#define NT 2048
#define ND 256
#define NH 256
#define NTHR 512
#define CHUNK 32
#define NCHUNK (NT / CHUNK)   // 64

__device__ __forceinline__ float sigmoid_f(float x) { return 1.f / (1.f + __expf(-x)); }
__device__ __forceinline__ float tanh_f(float x)    { return 1.f - 2.f / (1.f + __expf(2.f * x)); }
__device__ __forceinline__ half2_t mkh2(float a, float b) {
    half2_t r; r.x = (_Float16)a; r.y = (_Float16)b; return r;
}
__device__ __forceinline__ float h2get(unsigned u, int idx) {
    half2_t h = __builtin_bit_cast(half2_t, u);
    return idx ? (float)h.y : (float)h.x;
}

// Grid 256 x 512, all co-resident (1 WG/CU).
//  bid <  64 : consumer — full GRU recurrence for batch=bid, h-part weights in VGPRs,
//              LDS-only per-step exchange (2 barriers/step). Polls producer flags 1x/32 steps.
//  bid >= 64 : producer (gate g, batch b) — x-projections pre[t][c] = b_g[c] + x_t . Wg[0:256,c]
//              into a ring in ws (fp16 col-pair packed), RELAXED agent atomics + vmcnt drain
//              before flag store. No acquire/release => no buffer_inv/wbl2 storms.
extern "C" __global__ void __launch_bounds__(NTHR, 1)
gru_fused(const float* __restrict__ x,
          const float* __restrict__ Wz, const float* __restrict__ bz,
          const float* __restrict__ Wr, const float* __restrict__ br,
          const float* __restrict__ Wh, const float* __restrict__ bh,
          float* __restrict__ out,
          unsigned* prodflag, unsigned* consflag,
          unsigned long long* preZR, unsigned* preH, int ring)
{
    __shared__ __align__(16) half2_t lds[32 * 128 + 8];
    const int tid = threadIdx.x;
    const int bid = blockIdx.x;
    const int rmask = ring - 1;

    if (bid >= NB) {
        // ---------------- producer ----------------
        const int pb = bid - NB;      // 0..191
        const int g  = pb >> 6;       // 0=z 1=r 2=h
        const int b  = pb & 63;
        const float* W    = (g == 0) ? Wz : (g == 1) ? Wr : Wh;
        const float* bias = (g == 0) ? bz : (g == 1) ? br : bh;
        const int c  = tid & 255;
        const int th = tid >> 8;      // t-half of chunk (16 steps each)

        half2_t w2[128];              // rows 0..255 (x part), col c
        #pragma unroll
        for (int i = 0; i < 128; ++i)
            w2[i] = mkh2(W[(2 * i) * NH + c], W[(2 * i + 1) * NH + c]);
        const float bv = bias[c];

        for (int ch = 0; ch < NCHUNK; ++ch) {
            // ring-space wait (consumer must be within ring-CHUNK steps)
            const int lead = ch * CHUNK + CHUNK - ring;
            if (lead > 0) {
                if (tid == 0) {
                    unsigned it = 0;
                    while ((int)__hip_atomic_load(&consflag[b], __ATOMIC_RELAXED,
                                                  __HIP_MEMORY_SCOPE_AGENT) < lead) {
                        __builtin_amdgcn_s_sleep(8);
                        if (++it > (1u << 20)) break;
                    }
                }
                __syncthreads();
            }
            // stage x[b][t0..t0+31][:] into LDS as half2
            const int t0 = ch * CHUNK;
            {
                const float4* xs = reinterpret_cast<const float4*>(
                    x + (size_t)b * NT * ND + (size_t)t0 * ND);
                #pragma unroll
                for (int rep = 0; rep < 4; ++rep) {
                    const int idx = rep * NTHR + tid;    // 0..2047 float4s
                    const float4 v = xs[idx];
                    lds[idx * 2]     = mkh2(v.x, v.y);
                    lds[idx * 2 + 1] = mkh2(v.z, v.w);
                }
            }
            __syncthreads();
            #pragma unroll 1
            for (int i = 0; i < 16; ++i) {
                const int tt = th * 16 + i;
                const half2_t* xr = &lds[tt * 128];
                float a = 0.f;
                #pragma unroll
                for (int k = 0; k < 128; ++k)
                    a = __builtin_amdgcn_fdot2(xr[k], w2[k], a, false);
                a += bv;
                const float an = __shfl_xor(a, 1, 64);
                if (!(c & 1)) {
                    const unsigned pk = __builtin_bit_cast(unsigned, mkh2(a, an));
                    const size_t slot = (size_t)b * ring + ((t0 + tt) & rmask);
                    if (g == 2) {
                        __hip_atomic_store(&preH[slot * 128 + (c >> 1)], pk,
                                           __ATOMIC_RELAXED, __HIP_MEMORY_SCOPE_AGENT);
                    } else {
                        unsigned* zr32 = reinterpret_cast<unsigned*>(&preZR[slot * 128 + (c >> 1)]);
                        __hip_atomic_store(&zr32[g], pk,
                                           __ATOMIC_RELAXED, __HIP_MEMORY_SCOPE_AGENT);
                    }
                }
            }
            asm volatile("s_waitcnt vmcnt(0)" ::: "memory");  // drain own stores
            __syncthreads();                                   // all waves drained
            if (tid == 0)
                __hip_atomic_store(&prodflag[b * 3 + g], (unsigned)(ch + 1),
                                   __ATOMIC_RELAXED, __HIP_MEMORY_SCOPE_AGENT);
            __syncthreads();
        }
        return;
    }

    // ---------------- consumer: recurrence for batch b ----------------
    const int b    = bid;
    const int c    = tid >> 1;       // output column 0..255
    const int half = tid & 1;        // k-half of the 256 h inputs
    half2_t* hbuf2 = lds;            // [128] packed h_prev
    half2_t* vbuf2 = lds + 128;      // [128] packed r*h_prev

    half2_t wzh[64], wrh[64], whh[64];   // rows 256+half*128 .. +127, col c
    {
        const int kb = ND + half * 128;
        #pragma unroll
        for (int i = 0; i < 64; ++i) {
            wzh[i] = mkh2(Wz[(kb + 2 * i) * NH + c], Wz[(kb + 2 * i + 1) * NH + c]);
            wrh[i] = mkh2(Wr[(kb + 2 * i) * NH + c], Wr[(kb + 2 * i + 1) * NH + c]);
            whh[i] = mkh2(Wh[(kb + 2 * i) * NH + c], Wh[(kb + 2 * i + 1) * NH + c]);
        }
    }
    if (tid < 256) lds[tid] = mkh2(0.f, 0.f);   // zero hbuf2+vbuf2
    float hreg = 0.f;

    // wait for chunk 0 of all 3 gates
    if (tid < 3) {
        unsigned it = 0;
        while (__hip_atomic_load(&prodflag[b * 3 + tid], __ATOMIC_RELAXED,
                                 __HIP_MEMORY_SCOPE_AGENT) < 1u) {
            __builtin_amdgcn_s_sleep(8);
            if (++it > (1u << 20)) break;
        }
    }
    __syncthreads();

    const int sub = c & 1;           // which half of the packed col-pair
    unsigned long long zr = __hip_atomic_load(&preZR[(size_t)b * ring * 128 + (c >> 1)],
                                              __ATOMIC_RELAXED, __HIP_MEMORY_SCOPE_AGENT);
    unsigned hh = __hip_atomic_load(&preH[(size_t)b * ring * 128 + (c >> 1)],
                                    __ATOMIC_RELAXED, __HIP_MEMORY_SCOPE_AGENT);
    float* outb = out + (size_t)b * NT * NH + c;

    for (int t = 0; t < NT; ++t) {
        // ---- stage A: z, r ----
        const half2_t* hsrc = hbuf2 + half * 64;
        float az = 0.f, ar = 0.f;
        #pragma unroll
        for (int i = 0; i < 64; ++i) {
            const half2_t hv = hsrc[i];
            az = __builtin_amdgcn_fdot2(hv, wzh[i], az, false);
            ar = __builtin_amdgcn_fdot2(hv, wrh[i], ar, false);
        }
        az += __shfl_xor(az, 1, 64);
        ar += __shfl_xor(ar, 1, 64);
        const float z = sigmoid_f(az + h2get((unsigned)(zr & 0xffffffffu), sub));
        const float r = sigmoid_f(ar + h2get((unsigned)(zr >> 32), sub));
        const float v  = r * hreg;
        const float v1 = __shfl_xor(v, 2, 64);
        if (!(tid & 3)) vbuf2[c >> 1] = mkh2(v, v1);
        __syncthreads();   // barA: vbuf2 ready

        // ---- stage B: h_hat, h_new ----
        const half2_t* vsrc = vbuf2 + half * 64;
        float ah = 0.f;
        #pragma unroll
        for (int i = 0; i < 64; ++i)
            ah = __builtin_amdgcn_fdot2(vsrc[i], whh[i], ah, false);
        ah += __shfl_xor(ah, 1, 64);
        const float hhat = tanh_f(ah + h2get(hh, sub));
        const float hn = hreg + z * (hhat - hreg);
        hreg = hn;
        if (!half) outb[(size_t)t * NH] = hn;
        const float hn1 = __shfl_xor(hn, 2, 64);
        if (!(tid & 3)) hbuf2[c >> 1] = mkh2(hn, hn1);

        const int tn = t + 1;
        if (tn < NT && (tn & (CHUNK - 1)) != 0) {
            // prefetch next step's pre (same ready chunk)
            const size_t sl = ((size_t)b * ring + (tn & rmask)) * 128 + (c >> 1);
            zr = __hip_atomic_load(&preZR[sl], __ATOMIC_RELAXED, __HIP_MEMORY_SCOPE_AGENT);
            hh = __hip_atomic_load(&preH[sl], __ATOMIC_RELAXED, __HIP_MEMORY_SCOPE_AGENT);
        }
        __syncthreads();   // barB: hbuf2 = h_t everywhere

        if (tn < NT && (tn & (CHUNK - 1)) == 0) {
            if (tid == 0)   // publish progress (ring reuse gate)
                __hip_atomic_store(&consflag[b], (unsigned)tn,
                                   __ATOMIC_RELAXED, __HIP_MEMORY_SCOPE_AGENT);
            const unsigned need = (unsigned)((tn >> 5) + 1);
            if (tid < 3) {
                unsigned it = 0;
                while (__hip_atomic_load(&prodflag[b * 3 + tid], __ATOMIC_RELAXED,
                                         __HIP_MEMORY_SCOPE_AGENT) < need) {
                    __builtin_amdgcn_s_sleep(8);
                    if (++it > (1u << 20)) break;
                }
            }
            __syncthreads();
            const size_t sl = ((size_t)b * ring + (tn & rmask)) * 128 + (c >> 1);
            zr = __hip_atomic_load(&preZR[sl], __ATOMIC_RELAXED, __HIP_MEMORY_SCOPE_AGENT);
            hh = __hip_atomic_load(&preH[sl], __ATOMIC_RELAXED, __HIP_MEMORY_SCOPE_AGENT);
        }
    }
}

extern "C" void kernel_launch(void* const* d_in, const int* in_sizes, int n_in,
                              void* d_out, int out_size, void* d_ws, size_t ws_size,
                              hipStream_t stream) {
    const float* x  = (const float*)d_in[0];
    const float* Wz = (const float*)d_in[1];
    const float* bz = (const float*)d_in[2];
    const float* Wr = (const float*)d_in[3];
    const float* br = (const float*)d_in[4];
    const float* Wh = (const float*)d_in[5];
    const float* bh = (const float*)d_in[6];
    float* outp = (float*)d_out;

    // ring sizing: per ring-step bytes = NB*128*12 = 96 KiB
    const size_t base = 4096;
    int ring = 32;
    for (int r = 2048; r >= 32; r >>= 1) {
        const size_t need = base + (size_t)NB * r * 128 * 12;
        if (need <= ws_size) { ring = r; break; }
    }
    char* w = (char*)d_ws;
    unsigned* prodflag = (unsigned*)w;                 // [64][3]
    unsigned* consflag = (unsigned*)(w + 1024);        // [64]
    unsigned long long* preZR = (unsigned long long*)(w + base);          // [64][ring][128]
    unsigned* preH = (unsigned*)(w + base + (size_t)NB * ring * 128 * 8); // [64][ring][128]

    hipMemsetAsync(w, 0, 4096, stream);  // flags must start at 0 each launch
    gru_fused<<<256, NTHR, 0, stream>>>(x, Wz, bz, Wr, br, Wh, bh, outp,
                                        prodflag, consflag, preZR, preH, ring);
}